// Round 5
// baseline (3467.314 us; speedup 1.0000x reference)
//
#include <hip/hip_runtime.h>

#define DIVUP(a,b) (((a)+(b)-1)/(b))

// ---------------------------------------------------------------------------
__global__ void bcast_anchor_kernel(const float* __restrict__ a, float* __restrict__ out) {
    int i = blockIdx.x * 256 + threadIdx.x;   // over 3*127*127 = 48387
    int b = blockIdx.y;
    if (i < 48387) out[b * 48387 + i] = a[i];
}

// ---------------------------------------------------------------------------
// conv K=4 s=2 VALID + ReLU body: OCT ocs x 4 x-pixels per thread.
// Tail x-tiles shift left (overlapping threads write identical values).
template<int OCT>
__device__ __forceinline__ void conv4s2_body(int bx, int ocg, int b, int Cout,
    const float* __restrict__ in, const float* __restrict__ w, const float* __restrict__ bias,
    float* __restrict__ out, int Cin, int Hin, int Win, int Hout, int Wout, float* sw)
{
    const int nw = OCT * Cin * 16;
    const float* wb = w + (size_t)ocg * nw;
    for (int i = threadIdx.x; i < nw; i += 256) sw[i] = wb[i];
    __syncthreads();
    const int TX = (Wout + 3) >> 2;
    const int t  = bx * 256 + threadIdx.x;
    if (t >= Hout * TX) return;
    const int oy = t / TX, tx = t - oy * TX;
    int ox0 = tx * 4; if (ox0 > Wout - 4) ox0 = Wout - 4;

    const float* ip = in + ((size_t)(b * Cin) * Hin + 2 * oy) * Win + 2 * ox0;
    float acc[OCT][4];
    #pragma unroll
    for (int o = 0; o < OCT; ++o) {
        float z = bias[ocg * OCT + o];
        acc[o][0] = z; acc[o][1] = z; acc[o][2] = z; acc[o][3] = z;
    }
    for (int ic = 0; ic < Cin; ++ic) {
        const float* r = ip + (size_t)ic * Hin * Win;
        #pragma unroll
        for (int ky = 0; ky < 4; ++ky) {
            const float* rr = r + ky * Win;
            float x0 = rr[0], x1 = rr[1], x2 = rr[2], x3 = rr[3], x4 = rr[4],
                  x5 = rr[5], x6 = rr[6], x7 = rr[7], x8 = rr[8], x9 = rr[9];
            #pragma unroll
            for (int o = 0; o < OCT; ++o) {
                const float* wk = sw + ((o * Cin + ic) * 4 + ky) * 4;
                float w0 = wk[0], w1 = wk[1], w2 = wk[2], w3 = wk[3];
                acc[o][0] = fmaf(x0, w0, fmaf(x1, w1, fmaf(x2, w2, fmaf(x3, w3, acc[o][0]))));
                acc[o][1] = fmaf(x2, w0, fmaf(x3, w1, fmaf(x4, w2, fmaf(x5, w3, acc[o][1]))));
                acc[o][2] = fmaf(x4, w0, fmaf(x5, w1, fmaf(x6, w2, fmaf(x7, w3, acc[o][2]))));
                acc[o][3] = fmaf(x6, w0, fmaf(x7, w1, fmaf(x8, w2, fmaf(x9, w3, acc[o][3]))));
            }
        }
    }
    float* op = out + (((size_t)b * Cout + ocg * OCT) * Hout + oy) * Wout + ox0;
    #pragma unroll
    for (int o = 0; o < OCT; ++o) {
        float* q = op + (size_t)o * Hout * Wout;
        q[0] = fmaxf(acc[o][0], 0.0f); q[1] = fmaxf(acc[o][1], 0.0f);
        q[2] = fmaxf(acc[o][2], 0.0f); q[3] = fmaxf(acc[o][3], 0.0f);
    }
}

// plain 3D-grid version: grid (tiles, Cout/OCT, B)
template<int OCT>
__global__ void conv4s2_relu_t(const float* __restrict__ in, const float* __restrict__ w,
                               const float* __restrict__ bias, float* __restrict__ out,
                               int Cin, int Hin, int Win, int Hout, int Wout)
{
    __shared__ float sw[4096];
    conv4s2_body<OCT>(blockIdx.x, blockIdx.y, blockIdx.z, gridDim.y * OCT,
                      in, w, bias, out, Cin, Hin, Win, Hout, Wout, sw);
}

// XCD-swizzled 1D version: id%8 = XCD (heuristic); sample z pinned to 8/gz XCDs
// so its input stays in that XCD's private L2. Requires gz in {1,2,4,8}.
template<int OCT>
__global__ void conv4s2_relu_sw(const float* __restrict__ in, const float* __restrict__ w,
                                const float* __restrict__ bias, float* __restrict__ out,
                                int Cin, int Hin, int Win, int Hout, int Wout,
                                int gx, int gy, int gz)
{
    __shared__ float sw[4096];
    const int id = blockIdx.x;
    const int k = 8 / gz;                 // XCDs per sample
    const int xcd = id & 7, slot = id >> 3;
    const int z = xcd / k;
    const int inner = slot * k + (xcd % k);
    const int x = inner % gx, y = inner / gx;
    conv4s2_body<OCT>(x, y, z, gy * OCT,
                      in, w, bias, out, Cin, Hin, Win, Hout, Wout, sw);
}

// ---------------------------------------------------------------------------
// fused VAE head: mu = h*mw+mb, logvar = h*lw+lb, z = mu + eps*exp(0.5*logvar)
__global__ void vae_head_kernel(const float* __restrict__ h, const float* __restrict__ mw,
                                const float* __restrict__ mb, const float* __restrict__ lw,
                                const float* __restrict__ lb, const float* __restrict__ eps,
                                float* __restrict__ mu_out, float* __restrict__ lv_out,
                                float* __restrict__ z_out)
{
    const int idx = blockIdx.x * 256 + threadIdx.x;   // over 64*32*196
    if (idx >= 64 * 32 * 196) return;
    const int p  = idx % 196;
    const int oc = (idx / 196) % 32;
    const int b  = idx / (196 * 32);
    const float* hb = h + (b * 64) * 196 + p;
    float am = mb[oc], al = lb[oc];
    for (int ic = 0; ic < 64; ++ic) {
        float hv = hb[ic * 196];
        am = fmaf(hv, mw[oc * 64 + ic], am);
        al = fmaf(hv, lw[oc * 64 + ic], al);
    }
    mu_out[idx] = am;
    lv_out[idx] = al;
    z_out[idx]  = fmaf(eps[idx], expf(0.5f * al), am);
}

// ---------------------------------------------------------------------------
__global__ void conv1x1_relu_kernel(const float* __restrict__ in, const float* __restrict__ w,
                                    const float* __restrict__ bias, float* __restrict__ out,
                                    int Cin, int Cout, int HW, int total)
{
    const int idx = blockIdx.x * 256 + threadIdx.x;
    if (idx >= total) return;
    const int p  = idx % HW;
    const int oc = (idx / HW) % Cout;
    const int b  = idx / (HW * Cout);
    const float* ib = in + (b * Cin) * HW + p;
    float acc = bias[oc];
    for (int ic = 0; ic < Cin; ++ic) acc = fmaf(ib[ic * HW], w[oc * Cin + ic], acc);
    out[idx] = fmaxf(acc, 0.0f);
}

// ---------------------------------------------------------------------------
// transposed conv K=4 s=2 VALID + ReLU, 4-oc-tiled, taps hoisted & padded to 4.
__global__ void deconv4s2x4_relu_kernel(const float* __restrict__ in, const float* __restrict__ w,
                                        const float* __restrict__ bias, float* __restrict__ out,
                                        int Cin, int Hin, int Win, int Hout, int Wout)
{
    const int ocg = blockIdx.y, b = blockIdx.z, Cout = gridDim.y * 4;
    __shared__ float sw[4096];
    const int nw = 4 * Cin * 16;
    const float* wb = w + (size_t)ocg * nw;
    for (int i = threadIdx.x; i < nw; i += 256) sw[i] = wb[i];
    __syncthreads();
    const int p = blockIdx.x * 256 + threadIdx.x;
    if (p >= Hout * Wout) return;
    const int oy = p / Wout, ox = p - oy * Wout;
    int off[4], wo[4], nt = 0;
    #pragma unroll
    for (int ky = 0; ky < 4; ++ky) {
        int t = oy + ky - 3;
        if (t < 0 || (t & 1) || (t >> 1) >= Hin) continue;
        #pragma unroll
        for (int kx = 0; kx < 4; ++kx) {
            int u = ox + kx - 3;
            if (u < 0 || (u & 1) || (u >> 1) >= Win) continue;
            off[nt] = (t >> 1) * Win + (u >> 1);
            wo[nt]  = ky * 4 + kx;
            ++nt;
        }
    }
    #pragma unroll
    for (int j = 1; j < 4; ++j) if (j >= nt) { off[j] = off[0]; wo[j] = wo[0]; }
    const bool m1 = 1 < nt, m2 = 2 < nt, m3 = 3 < nt;
    float a0 = bias[ocg*4+0], a1 = bias[ocg*4+1], a2 = bias[ocg*4+2], a3 = bias[ocg*4+3];
    const float* ib = in + (size_t)(b * Cin) * Hin * Win;
    for (int ic = 0; ic < Cin; ++ic) {
        const float* base = ib + (size_t)ic * Hin * Win;
        float x0 = base[off[0]];
        float x1 = m1 ? base[off[1]] : 0.0f;
        float x2 = m2 ? base[off[2]] : 0.0f;
        float x3 = m3 ? base[off[3]] : 0.0f;
        const float* wc0 = sw + (0 * Cin + ic) * 16;
        const float* wc1 = sw + (1 * Cin + ic) * 16;
        const float* wc2 = sw + (2 * Cin + ic) * 16;
        const float* wc3 = sw + (3 * Cin + ic) * 16;
        a0 = fmaf(x0, wc0[wo[0]], fmaf(x1, wc0[wo[1]], fmaf(x2, wc0[wo[2]], fmaf(x3, wc0[wo[3]], a0))));
        a1 = fmaf(x0, wc1[wo[0]], fmaf(x1, wc1[wo[1]], fmaf(x2, wc1[wo[2]], fmaf(x3, wc1[wo[3]], a1))));
        a2 = fmaf(x0, wc2[wo[0]], fmaf(x1, wc2[wo[1]], fmaf(x2, wc2[wo[2]], fmaf(x3, wc2[wo[3]], a2))));
        a3 = fmaf(x0, wc3[wo[0]], fmaf(x1, wc3[wo[1]], fmaf(x2, wc3[wo[2]], fmaf(x3, wc3[wo[3]], a3))));
    }
    float* op = out + (((size_t)b * Cout + ocg * 4) * Hout + oy) * Wout + ox;
    const size_t st = (size_t)Hout * Wout;
    op[0] = fmaxf(a0, 0.0f); op[st] = fmaxf(a1, 0.0f);
    op[2*st] = fmaxf(a2, 0.0f); op[3*st] = fmaxf(a3, 0.0f);
}

// ---------------------------------------------------------------------------
// transposed conv K=5 stride=2 VALID + sigmoid (pad_a = 4).  w: (Cout,Cin,5,5)
__global__ void deconv5s2_sigmoid_kernel(const float* __restrict__ in, const float* __restrict__ w,
                                         const float* __restrict__ bias, float* __restrict__ out,
                                         int Cin, int Hin, int Win, int Hout, int Wout)
{
    const int oc = blockIdx.y, b = blockIdx.z, Cout = gridDim.y;
    __shared__ float sw[512];
    const int nw = Cin * 25;
    for (int i = threadIdx.x; i < nw; i += blockDim.x) sw[i] = w[oc * nw + i];
    __syncthreads();
    const int p = blockIdx.x * blockDim.x + threadIdx.x;
    if (p >= Hout * Wout) return;
    const int oy = p / Wout, ox = p - oy * Wout;
    int iys[3], kys[3], niy = 0;
    int ixs[3], kxs[3], nix = 0;
    #pragma unroll
    for (int k = 0; k < 5; ++k) {
        int t = oy + k - 4;
        if (t >= 0 && !(t & 1) && (t >> 1) < Hin) { iys[niy] = t >> 1; kys[niy] = k; ++niy; }
        int u = ox + k - 4;
        if (u >= 0 && !(u & 1) && (u >> 1) < Win) { ixs[nix] = u >> 1; kxs[nix] = k; ++nix; }
    }
    float acc = bias[oc];
    for (int ic = 0; ic < Cin; ++ic) {
        const float* ib = in + ((b * Cin + ic) * Hin) * Win;
        const float* wc = sw + ic * 25;
        for (int a = 0; a < niy; ++a)
            for (int c2 = 0; c2 < nix; ++c2)
                acc = fmaf(ib[iys[a] * Win + ixs[c2]], wc[kys[a] * 5 + kxs[c2]], acc);
    }
    out[((b * Cout + oc) * Hout + oy) * Wout + ox] = 1.0f / (1.0f + expf(-acc));
}

// ---------------------------------------------------------------------------
// per-sample xcorr, 16-way channel split: grid (nb, 16), 320 thr, 4 ch/group.
// f: (nb,64,30,30), af: (64,14,14), out[b*289+p] += partial (atomic; pre-zeroed)
__global__ void xcorr_split_kernel(const float* __restrict__ f, const float* __restrict__ af,
                                   float* __restrict__ out)
{
    __shared__ float s_af[4 * 196];
    const int b = blockIdx.x, g = blockIdx.y;
    for (int i = threadIdx.x; i < 4 * 196; i += 320) s_af[i] = af[g * 4 * 196 + i];
    __syncthreads();
    const int p = threadIdx.x;
    if (p >= 289) return;
    const int oy = p / 17, ox = p - oy * 17;
    const float* fb = f + ((size_t)b * 64 + g * 4) * 900 + oy * 30 + ox;
    float acc = 0.0f;
    for (int c = 0; c < 4; ++c) {
        const float* fc = fb + c * 900;
        const float* ac = s_af + c * 196;
        #pragma unroll
        for (int ky = 0; ky < 14; ++ky) {
            const float* fr = fc + ky * 30;
            const float* ar = ac + ky * 14;
            #pragma unroll
            for (int kx = 0; kx < 14; ++kx)
                acc = fmaf(fr[kx], ar[kx], acc);
        }
    }
    atomicAdd(&out[b * 289 + p], acc);
}

// ---------------------------------------------------------------------------
extern "C" void kernel_launch(void* const* d_in, const int* in_sizes, int n_in,
                              void* d_out, int out_size, void* d_ws, size_t ws_size,
                              hipStream_t stream)
{
    const float* pos         = (const float*)d_in[0];
    const float* neg         = (const float*)d_in[1];
    const float* pos_crop    = (const float*)d_in[2];
    const float* eps         = (const float*)d_in[3];
    const float* anchor_crop = (const float*)d_in[4];
    const float* ew1 = (const float*)d_in[5];  const float* eb1 = (const float*)d_in[6];
    const float* ew2 = (const float*)d_in[7];  const float* eb2 = (const float*)d_in[8];
    const float* ew3 = (const float*)d_in[9];  const float* eb3 = (const float*)d_in[10];
    const float* mw  = (const float*)d_in[11]; const float* mb  = (const float*)d_in[12];
    const float* lw  = (const float*)d_in[13]; const float* lb  = (const float*)d_in[14];
    const float* dw0 = (const float*)d_in[15]; const float* db0 = (const float*)d_in[16];
    const float* dw1 = (const float*)d_in[17]; const float* db1 = (const float*)d_in[18];
    const float* dw2 = (const float*)d_in[19]; const float* db2 = (const float*)d_in[20];
    const float* dw3 = (const float*)d_in[21]; const float* db3 = (const float*)d_in[22];

    float* out = (float*)d_out;
    float* ws  = (float*)d_ws;

    // output offsets (floats): anchor, cxp, cxn, recon, mu, logvar
    float* o_anchor = out;
    float* o_cxp    = out + 3096768;
    float* o_cxn    = out + 3115264;
    float* o_recon  = out + 3133760;
    float* o_mu     = out + 6230528;
    float* o_lv     = out + 6631936;

    // ---- workspace
    float* AF = ws;                 // anchor features 64*14*14, persistent
    float* A  = ws + 12544;

    // Phase A (anchor enc, B=1)
    float* AH1 = A;                 // 32*62*62
    float* AH2 = A + 123008;        // 64*30*30
    // Phase B (VAE, 8-sample chunks): proven offsets
    float* E1  = A;                 // 8*32*62*62
    float* E2  = A + 984064;        // 8*64*30*30
    float* CH3 = A + 1444864;       // 64*64*14*14
    float* Z   = A;                 // 64*32*14*14
    float* D0  = A + 401408;        // 64*64*14*14
    float* D1  = A + 1204224;       // 64*32*30*30
    float* D2c = A;                 // 16*16*62*62 (chunk)
    // Phase C (branches): F1 CB*508032 ; F2 CB*245952 ; F3 overlays F1 (dead
    // after conv2).  per-sample 753984 floats.
    long nf = (long)(ws_size / 4);
    int CB = (8L * 753984 + 12544 <= nf) ? 8 : 4;
    float* F1 = A;
    float* F2 = A + (size_t)CB * 508032;
    float* F3 = A;                  // overlay

    // 1) anchor output = broadcast input
    bcast_anchor_kernel<<<dim3(189, 64), 256, 0, stream>>>(anchor_crop, o_anchor);

    // 2) Phase A: anchor encoder, B=1
    conv4s2_relu_t<2><<<dim3(4, 16, 1), 256, 0, stream>>>(anchor_crop, ew1, eb1, AH1, 3, 127, 127, 62, 62);
    conv4s2_relu_t<2><<<dim3(1, 32, 1), 256, 0, stream>>>(AH1, ew2, eb2, AH2, 32, 62, 62, 30, 30);
    conv4s2_relu_t<2><<<dim3(1, 32, 1), 256, 0, stream>>>(AH2, ew3, eb3, AF, 64, 30, 30, 14, 14);

    // 3) Phase B: VAE encoder on pos_crop, 8-sample chunks -> CH3
    for (int c = 0; c < 8; ++c) {
        const float* inp = pos_crop + (size_t)c * 8 * 48387;
        conv4s2_relu_t<2><<<dim3(4, 16, 8), 256, 0, stream>>>(inp, ew1, eb1, E1, 3, 127, 127, 62, 62);
        conv4s2_relu_t<2><<<dim3(1, 32, 8), 256, 0, stream>>>(E1, ew2, eb2, E2, 32, 62, 62, 30, 30);
        conv4s2_relu_t<2><<<dim3(1, 32, 8), 256, 0, stream>>>(E2, ew3, eb3, CH3 + (size_t)c * 8 * 12544, 64, 30, 30, 14, 14);
    }
    //    head + decoder
    vae_head_kernel<<<1568, 256, 0, stream>>>(CH3, mw, mb, lw, lb, eps, o_mu, o_lv, Z);
    conv1x1_relu_kernel<<<3136, 256, 0, stream>>>(Z, dw0, db0, D0, 32, 64, 196, 64*64*196);
    deconv4s2x4_relu_kernel<<<dim3(4, 8, 64), 256, 0, stream>>>(D0, dw1, db1, D1, 64, 14, 14, 30, 30);
    for (int c = 0; c < 4; ++c) {
        deconv4s2x4_relu_kernel<<<dim3(16, 4, 16), 256, 0, stream>>>(D1 + (size_t)c * 16 * 28800, dw2, db2, D2c, 32, 30, 30, 62, 62);
        deconv5s2_sigmoid_kernel<<<dim3(64, 3, 16), 256, 0, stream>>>(D2c, dw3, db3, o_recon + (size_t)c * 16 * 48387, 16, 62, 62, 127, 127);
    }

    // 4) Phase C: siamese branches, merged pos+neg stream, CB-sample chunks,
    //    XCD-swizzled convs (sample pinned to 8/CB XCDs for L2 locality)
    hipMemsetAsync(o_cxp, 0, 2 * 18496 * sizeof(float), stream);  // cxp+cxn contiguous
    const int nchunks = 128 / CB;
    for (int c = 0; c < nchunks; ++c) {
        const int s0 = c * CB;   // CB divides 64 -> no pos/neg straddle
        const float* inp  = (s0 < 64) ? pos + (size_t)s0 * 195075 : neg + (size_t)(s0 - 64) * 195075;
        float*       o_cx = (s0 < 64) ? o_cxp + (size_t)s0 * 289  : o_cxn + (size_t)(s0 - 64) * 289;
        conv4s2_relu_sw<2><<<16 * 16 * CB, 256, 0, stream>>>(inp, ew1, eb1, F1, 3, 255, 255, 126, 126, 16, 16, CB);
        conv4s2_relu_sw<2><<<4 * 32 * CB, 256, 0, stream>>>(F1, ew2, eb2, F2, 32, 126, 126, 62, 62, 4, 32, CB);
        conv4s2_relu_sw<2><<<1 * 32 * CB, 256, 0, stream>>>(F2, ew3, eb3, F3, 64, 62, 62, 30, 30, 1, 32, CB);
        xcorr_split_kernel<<<dim3(CB, 16), 320, 0, stream>>>(F3, AF, o_cx);
    }
}

// Round 6
// 1846.086 us; speedup vs baseline: 1.8782x; 1.8782x over previous
//
#include <hip/hip_runtime.h>

#define DIVUP(a,b) (((a)+(b)-1)/(b))

// ---------------------------------------------------------------------------
__global__ void bcast_anchor_kernel(const float* __restrict__ a, float* __restrict__ out) {
    int i = blockIdx.x * 256 + threadIdx.x;   // over 3*127*127 = 48387
    int b = blockIdx.y;
    if (i < 48387) out[b * 48387 + i] = a[i];
}

// ---------------------------------------------------------------------------
// conv K=4 s=2 VALID + ReLU: OCT ocs x 4 x-pixels per thread.
// Weights/bias read directly from global with wave-uniform indices -> s_load.
// VEC: float2 input loads (requires even Win and even base offsets).
// grid: (ceil(Hout*ceil(Wout/4)/256), Cout/OCT, B). Tail x-tiles shift left.
template<int OCT, bool VEC>
__global__ void conv4s2_relu_k(const float* __restrict__ in, const float* __restrict__ w,
                               const float* __restrict__ bias, float* __restrict__ out,
                               int Cin, int Hin, int Win, int Hout, int Wout)
{
    const int ocg = blockIdx.y, b = blockIdx.z, Cout = gridDim.y * OCT;
    const int TX = (Wout + 3) >> 2;
    const int t  = blockIdx.x * 256 + threadIdx.x;
    if (t >= Hout * TX) return;
    const int oy = t / TX, tx = t - oy * TX;
    int ox0 = tx * 4; if (ox0 > Wout - 4) ox0 = Wout - 4;

    const float* ip = in + ((size_t)(b * Cin) * Hin + 2 * oy) * Win + 2 * ox0;
    const float* wb = w + (size_t)ocg * OCT * Cin * 16;
    float acc[OCT][4];
    #pragma unroll
    for (int o = 0; o < OCT; ++o) {
        float z = bias[ocg * OCT + o];
        acc[o][0] = z; acc[o][1] = z; acc[o][2] = z; acc[o][3] = z;
    }
    for (int ic = 0; ic < Cin; ++ic) {
        const float* r = ip + (size_t)ic * Hin * Win;
        #pragma unroll
        for (int ky = 0; ky < 4; ++ky) {
            const float* rr = r + ky * Win;
            float x0,x1,x2,x3,x4,x5,x6,x7,x8,x9;
            if (VEC) {
                const float2* rv = (const float2*)rr;
                float2 p0=rv[0], p1=rv[1], p2=rv[2], p3=rv[3], p4=rv[4];
                x0=p0.x; x1=p0.y; x2=p1.x; x3=p1.y; x4=p2.x;
                x5=p2.y; x6=p3.x; x7=p3.y; x8=p4.x; x9=p4.y;
            } else {
                x0=rr[0]; x1=rr[1]; x2=rr[2]; x3=rr[3]; x4=rr[4];
                x5=rr[5]; x6=rr[6]; x7=rr[7]; x8=rr[8]; x9=rr[9];
            }
            #pragma unroll
            for (int o = 0; o < OCT; ++o) {
                const float* wk = wb + ((o * Cin + ic) * 4 + ky) * 4;  // uniform -> s_load
                float w0 = wk[0], w1 = wk[1], w2 = wk[2], w3 = wk[3];
                acc[o][0] = fmaf(x0, w0, fmaf(x1, w1, fmaf(x2, w2, fmaf(x3, w3, acc[o][0]))));
                acc[o][1] = fmaf(x2, w0, fmaf(x3, w1, fmaf(x4, w2, fmaf(x5, w3, acc[o][1]))));
                acc[o][2] = fmaf(x4, w0, fmaf(x5, w1, fmaf(x6, w2, fmaf(x7, w3, acc[o][2]))));
                acc[o][3] = fmaf(x6, w0, fmaf(x7, w1, fmaf(x8, w2, fmaf(x9, w3, acc[o][3]))));
            }
        }
    }
    float* op = out + (((size_t)b * Cout + ocg * OCT) * Hout + oy) * Wout + ox0;
    #pragma unroll
    for (int o = 0; o < OCT; ++o) {
        float* q = op + (size_t)o * Hout * Wout;
        q[0] = fmaxf(acc[o][0], 0.0f); q[1] = fmaxf(acc[o][1], 0.0f);
        q[2] = fmaxf(acc[o][2], 0.0f); q[3] = fmaxf(acc[o][3], 0.0f);
    }
}

// ---------------------------------------------------------------------------
// fused VAE head
__global__ void vae_head_kernel(const float* __restrict__ h, const float* __restrict__ mw,
                                const float* __restrict__ mb, const float* __restrict__ lw,
                                const float* __restrict__ lb, const float* __restrict__ eps,
                                float* __restrict__ mu_out, float* __restrict__ lv_out,
                                float* __restrict__ z_out)
{
    const int idx = blockIdx.x * 256 + threadIdx.x;   // over 64*32*196
    if (idx >= 64 * 32 * 196) return;
    const int p  = idx % 196;
    const int oc = (idx / 196) % 32;
    const int b  = idx / (196 * 32);
    const float* hb = h + (b * 64) * 196 + p;
    float am = mb[oc], al = lb[oc];
    for (int ic = 0; ic < 64; ++ic) {
        float hv = hb[ic * 196];
        am = fmaf(hv, mw[oc * 64 + ic], am);
        al = fmaf(hv, lw[oc * 64 + ic], al);
    }
    mu_out[idx] = am;
    lv_out[idx] = al;
    z_out[idx]  = fmaf(eps[idx], expf(0.5f * al), am);
}

// ---------------------------------------------------------------------------
__global__ void conv1x1_relu_kernel(const float* __restrict__ in, const float* __restrict__ w,
                                    const float* __restrict__ bias, float* __restrict__ out,
                                    int Cin, int Cout, int HW, int total)
{
    const int idx = blockIdx.x * 256 + threadIdx.x;
    if (idx >= total) return;
    const int p  = idx % HW;
    const int oc = (idx / HW) % Cout;
    const int b  = idx / (HW * Cout);
    const float* ib = in + (b * Cin) * HW + p;
    float acc = bias[oc];
    for (int ic = 0; ic < Cin; ++ic) acc = fmaf(ib[ic * HW], w[oc * Cin + ic], acc);
    out[idx] = fmaxf(acc, 0.0f);
}

// ---------------------------------------------------------------------------
// transposed conv K=4 s=2 VALID + ReLU, parity-class form.
// oy = 2*oyi+py: exactly 2 y-taps iy={oyi-1,oyi} with ky={1-py,3-py} (borders masked).
// (Matches validated formula: oy = 2*iy + 3 - ky.)  Hout,Wout even.
// grid: (tilesPerClass*4, Cout/OCT, B); cls = blockIdx.x & 3.
template<int OCT>
__global__ void deconv4s2_relu_k(const float* __restrict__ in, const float* __restrict__ w,
                                 const float* __restrict__ bias, float* __restrict__ out,
                                 int Cin, int Hin, int Win, int Hout, int Wout)
{
    const int cls = blockIdx.x & 3, tile = blockIdx.x >> 2;
    const int py = cls >> 1, px = cls & 1;
    const int ocg = blockIdx.y, b = blockIdx.z, Cout = gridDim.y * OCT;
    const int H2 = Hout >> 1, W2 = Wout >> 1;
    const int t = tile * 256 + threadIdx.x;
    if (t >= H2 * W2) return;
    const int oyi = t / W2, oxi = t - oyi * W2;
    const int oy = 2 * oyi + py, ox = 2 * oxi + px;
    const bool my0 = oyi >= 1, my1 = oyi < Hin;
    const bool mx0 = oxi >= 1, mx1 = oxi < Win;
    const int iy0 = my0 ? oyi - 1 : 0, iy1 = my1 ? oyi : 0;
    const int ix0 = mx0 ? oxi - 1 : 0, ix1 = mx1 ? oxi : 0;
    const int ky0 = 1 - py, ky1 = 3 - py, kx0 = 1 - px, kx1 = 3 - px;  // uniform
    float acc[OCT];
    #pragma unroll
    for (int o = 0; o < OCT; ++o) acc[o] = bias[ocg * OCT + o];
    const float* ib = in + (size_t)(b * Cin) * Hin * Win;
    const float* wb = w + (size_t)ocg * OCT * Cin * 16;
    for (int ic = 0; ic < Cin; ++ic) {
        const float* base = ib + (size_t)ic * Hin * Win;
        float v00 = (my0 && mx0) ? base[iy0 * Win + ix0] : 0.0f;
        float v01 = (my0 && mx1) ? base[iy0 * Win + ix1] : 0.0f;
        float v10 = (my1 && mx0) ? base[iy1 * Win + ix0] : 0.0f;
        float v11 = (my1 && mx1) ? base[iy1 * Win + ix1] : 0.0f;
        #pragma unroll
        for (int o = 0; o < OCT; ++o) {
            const float* wc = wb + (size_t)(o * Cin + ic) * 16;   // uniform -> s_load
            acc[o] = fmaf(v00, wc[ky0 * 4 + kx0], fmaf(v01, wc[ky0 * 4 + kx1],
                     fmaf(v10, wc[ky1 * 4 + kx0], fmaf(v11, wc[ky1 * 4 + kx1], acc[o]))));
        }
    }
    float* op = out + (((size_t)b * Cout + ocg * OCT) * Hout + oy) * Wout + ox;
    const size_t st = (size_t)Hout * Wout;
    #pragma unroll
    for (int o = 0; o < OCT; ++o) op[o * st] = fmaxf(acc[o], 0.0f);
}

// ---------------------------------------------------------------------------
// transposed conv K=5 s=2 VALID + sigmoid, parity-class form, all 3 ocs/thread.
// Fixed sizes: Cin=16, Cout=3, Hin=Win=62, Hout=Wout=127.
// oy = 2*iy + 4 - ky  ->  class PY: taps iy = oyi + a - (NY-1), ky = 2*(a-(NY-1)) + 4 - PY.
template<int PY, int PX>
__device__ __forceinline__ void deconv5_body(int tile, int b,
    const float* __restrict__ in, const float* __restrict__ w,
    const float* __restrict__ bias, float* __restrict__ out)
{
    const int NY = PY ? 2 : 3, NX = PX ? 2 : 3;
    const int H2 = PY ? 63 : 64, W2 = PX ? 63 : 64;
    const int t = tile * 256 + threadIdx.x;
    if (t >= H2 * W2) return;
    const int oyi = t / W2, oxi = t - oyi * W2;
    const int oy = 2 * oyi + PY, ox = 2 * oxi + PX;
    int iy[3]; bool my[3];
    #pragma unroll
    for (int a = 0; a < NY; ++a) { int v = oyi + a - (NY - 1); my[a] = (v >= 0 && v < 62); iy[a] = my[a] ? v : 0; }
    int ix[3]; bool mx[3];
    #pragma unroll
    for (int c = 0; c < NX; ++c) { int v = oxi + c - (NX - 1); mx[c] = (v >= 0 && v < 62); ix[c] = mx[c] ? v : 0; }
    float a0 = bias[0], a1 = bias[1], a2 = bias[2];
    const float* ib = in + (size_t)(b * 16) * 3844;
    for (int ic = 0; ic < 16; ++ic) {
        const float* base = ib + ic * 3844;
        float v[3][3];
        #pragma unroll
        for (int a = 0; a < NY; ++a)
            #pragma unroll
            for (int c = 0; c < NX; ++c)
                v[a][c] = (my[a] && mx[c]) ? base[iy[a] * 62 + ix[c]] : 0.0f;
        #pragma unroll
        for (int a = 0; a < NY; ++a) {
            const int ky = 2 * (a - (NY - 1)) + 4 - PY;
            #pragma unroll
            for (int c = 0; c < NX; ++c) {
                const int kx = 2 * (c - (NX - 1)) + 4 - PX;
                const int wi = ky * 5 + kx;              // compile-time
                float vv = v[a][c];
                a0 = fmaf(vv, w[(0 * 16 + ic) * 25 + wi], a0);   // uniform -> s_load
                a1 = fmaf(vv, w[(1 * 16 + ic) * 25 + wi], a1);
                a2 = fmaf(vv, w[(2 * 16 + ic) * 25 + wi], a2);
            }
        }
    }
    float* o0 = out + (((size_t)b * 3 + 0) * 127 + oy) * 127 + ox;
    float* o1 = out + (((size_t)b * 3 + 1) * 127 + oy) * 127 + ox;
    float* o2 = out + (((size_t)b * 3 + 2) * 127 + oy) * 127 + ox;
    *o0 = 1.0f / (1.0f + expf(-a0));
    *o1 = 1.0f / (1.0f + expf(-a1));
    *o2 = 1.0f / (1.0f + expf(-a2));
}

__global__ void deconv5s2_sigmoid_k(const float* __restrict__ in, const float* __restrict__ w,
                                    const float* __restrict__ bias, float* __restrict__ out)
{
    const int cls = blockIdx.x & 3, tile = blockIdx.x >> 2, b = blockIdx.y;
    switch (cls) {
        case 0:  deconv5_body<0,0>(tile, b, in, w, bias, out); break;
        case 1:  deconv5_body<0,1>(tile, b, in, w, bias, out); break;
        case 2:  deconv5_body<1,0>(tile, b, in, w, bias, out); break;
        default: deconv5_body<1,1>(tile, b, in, w, bias, out); break;
    }
}

// ---------------------------------------------------------------------------
// per-sample xcorr, 16-way channel split, 2 x-px/thread.
// grid (nb, 16), 192 thr. f: (nb,64,30,30), af: (64,14,14) (uniform -> s_load),
// out[b*289+p] += partial (atomic; pre-zeroed).
__global__ void xcorr_split_kernel(const float* __restrict__ f, const float* __restrict__ af,
                                   float* __restrict__ out)
{
    const int b = blockIdx.x, g = blockIdx.y;
    const int idx = threadIdx.x;
    if (idx >= 153) return;                    // 17 rows x 9 x-tiles
    const int oy = idx / 9, tx = idx - oy * 9, ox = tx * 2;
    const float* fb = f + ((size_t)b * 64 + g * 4) * 900 + oy * 30 + ox;
    const float* ab = af + g * 4 * 196;
    float a0 = 0.0f, a1 = 0.0f;
    for (int c = 0; c < 4; ++c) {
        const float* fc = fb + c * 900;
        const float* ac = ab + c * 196;
        #pragma unroll
        for (int ky = 0; ky < 14; ++ky) {
            const float* fr = fc + ky * 30;
            const float* ar = ac + ky * 14;    // uniform -> s_load
            float v[15];
            #pragma unroll
            for (int k = 0; k < 15; ++k) v[k] = fr[k];
            #pragma unroll
            for (int k = 0; k < 14; ++k) {
                float wv = ar[k];
                a0 = fmaf(v[k],     wv, a0);
                a1 = fmaf(v[k + 1], wv, a1);
            }
        }
    }
    atomicAdd(&out[b * 289 + oy * 17 + ox], a0);
    if (ox + 1 < 17) atomicAdd(&out[b * 289 + oy * 17 + ox + 1], a1);
}

// ---------------------------------------------------------------------------
extern "C" void kernel_launch(void* const* d_in, const int* in_sizes, int n_in,
                              void* d_out, int out_size, void* d_ws, size_t ws_size,
                              hipStream_t stream)
{
    const float* pos         = (const float*)d_in[0];
    const float* neg         = (const float*)d_in[1];
    const float* pos_crop    = (const float*)d_in[2];
    const float* eps         = (const float*)d_in[3];
    const float* anchor_crop = (const float*)d_in[4];
    const float* ew1 = (const float*)d_in[5];  const float* eb1 = (const float*)d_in[6];
    const float* ew2 = (const float*)d_in[7];  const float* eb2 = (const float*)d_in[8];
    const float* ew3 = (const float*)d_in[9];  const float* eb3 = (const float*)d_in[10];
    const float* mw  = (const float*)d_in[11]; const float* mb  = (const float*)d_in[12];
    const float* lw  = (const float*)d_in[13]; const float* lb  = (const float*)d_in[14];
    const float* dw0 = (const float*)d_in[15]; const float* db0 = (const float*)d_in[16];
    const float* dw1 = (const float*)d_in[17]; const float* db1 = (const float*)d_in[18];
    const float* dw2 = (const float*)d_in[19]; const float* db2 = (const float*)d_in[20];
    const float* dw3 = (const float*)d_in[21]; const float* db3 = (const float*)d_in[22];

    float* out = (float*)d_out;
    float* ws  = (float*)d_ws;

    // output offsets (floats): anchor, cxp, cxn, recon, mu, logvar
    float* o_anchor = out;
    float* o_cxp    = out + 3096768;
    float* o_cxn    = out + 3115264;
    float* o_recon  = out + 3133760;
    float* o_mu     = out + 6230528;
    float* o_lv     = out + 6631936;

    // ---- workspace: AF persistent + arena (adaptive chunk sizes from ws_size)
    float* AF = ws;                 // anchor features 64*14*14
    float* A  = ws + 12544;
    const long budget = (long)(ws_size / 4) - 12544;

    // Phase B (VAE enc) chunk size
    const int CBV = budget >= 12361728L ? 64 : budget >= 6582272L ? 32
                  : budget >= 3692544L ? 16 : 8;
    float* E1  = A;                                   // CBV*32*62*62
    float* E2  = A + (size_t)CBV * 123008;            // CBV*64*30*30
    float* CH3 = E2 + (size_t)CBV * 57600;            // 64*64*14*14 (persistent in phase B)
    // Decoder
    const bool dec_full = budget >= 6983680L;
    float* Z   = A;                 // 64*32*14*14
    float* D0  = A + 401408;        // 64*64*14*14
    float* D1  = A + 1204224;       // 64*32*30*30
    float* D2  = A + 3047424;       // 64*16*62*62 (full mode)
    float* D2c = A;                 // 16*16*62*62 (chunk mode; overlays dead Z/D0)
    // Phase C (branches): F1 CB*508032 ; F2 CB*245952 ; F3 overlays F1
    const int CB = budget >= 24127488L ? 32 : budget >= 12063744L ? 16
                 : budget >= 6031872L ? 8 : 4;
    float* F1 = A;
    float* F2 = A + (size_t)CB * 508032;
    float* F3 = A;
    // anchor enc scratch
    float* AH1 = A;                 // 32*62*62
    float* AH2 = A + 123008;        // 64*30*30

    // 1) anchor output = broadcast input
    bcast_anchor_kernel<<<dim3(189, 64), 256, 0, stream>>>(anchor_crop, o_anchor);

    // 2) anchor encoder, B=1
    conv4s2_relu_k<4,false><<<dim3(4, 8, 1), 256, 0, stream>>>(anchor_crop, ew1, eb1, AH1, 3, 127, 127, 62, 62);
    conv4s2_relu_k<4,true ><<<dim3(1, 16, 1), 256, 0, stream>>>(AH1, ew2, eb2, AH2, 32, 62, 62, 30, 30);
    conv4s2_relu_k<4,true ><<<dim3(1, 16, 1), 256, 0, stream>>>(AH2, ew3, eb3, AF, 64, 30, 30, 14, 14);

    // 3) VAE encoder on pos_crop, CBV-sample chunks -> CH3
    for (int c = 0; c < 64 / CBV; ++c) {
        const float* inp = pos_crop + (size_t)c * CBV * 48387;
        conv4s2_relu_k<4,false><<<dim3(4, 8, CBV), 256, 0, stream>>>(inp, ew1, eb1, E1, 3, 127, 127, 62, 62);
        conv4s2_relu_k<4,true ><<<dim3(1, 16, CBV), 256, 0, stream>>>(E1, ew2, eb2, E2, 32, 62, 62, 30, 30);
        conv4s2_relu_k<4,true ><<<dim3(1, 16, CBV), 256, 0, stream>>>(E2, ew3, eb3, CH3 + (size_t)c * CBV * 12544, 64, 30, 30, 14, 14);
    }
    //    head + decoder
    vae_head_kernel<<<1568, 256, 0, stream>>>(CH3, mw, mb, lw, lb, eps, o_mu, o_lv, Z);
    conv1x1_relu_kernel<<<3136, 256, 0, stream>>>(Z, dw0, db0, D0, 32, 64, 196, 64*64*196);
    deconv4s2_relu_k<4><<<dim3(4, 8, 64), 256, 0, stream>>>(D0, dw1, db1, D1, 64, 14, 14, 30, 30);
    if (dec_full) {
        deconv4s2_relu_k<4><<<dim3(16, 4, 64), 256, 0, stream>>>(D1, dw2, db2, D2, 32, 30, 30, 62, 62);
        deconv5s2_sigmoid_k<<<dim3(64, 64), 256, 0, stream>>>(D2, dw3, db3, o_recon);
    } else {
        for (int c = 0; c < 4; ++c) {
            deconv4s2_relu_k<4><<<dim3(16, 4, 16), 256, 0, stream>>>(D1 + (size_t)c * 16 * 28800, dw2, db2, D2c, 32, 30, 30, 62, 62);
            deconv5s2_sigmoid_k<<<dim3(64, 16), 256, 0, stream>>>(D2c, dw3, db3, o_recon + (size_t)c * 16 * 48387);
        }
    }

    // 4) siamese branches, merged pos+neg stream, CB-sample chunks
    hipMemsetAsync(o_cxp, 0, 2 * 18496 * sizeof(float), stream);  // cxp+cxn contiguous
    const int nchunks = 128 / CB;
    for (int c = 0; c < nchunks; ++c) {
        const int s0 = c * CB;   // CB divides 64 -> no pos/neg straddle
        const float* inp  = (s0 < 64) ? pos + (size_t)s0 * 195075 : neg + (size_t)(s0 - 64) * 195075;
        float*       o_cx = (s0 < 64) ? o_cxp + (size_t)s0 * 289  : o_cxn + (size_t)(s0 - 64) * 289;
        conv4s2_relu_k<4,false><<<dim3(16, 8, CB), 256, 0, stream>>>(inp, ew1, eb1, F1, 3, 255, 255, 126, 126);
        conv4s2_relu_k<4,true ><<<dim3(4, 16, CB), 256, 0, stream>>>(F1, ew2, eb2, F2, 32, 126, 126, 62, 62);
        conv4s2_relu_k<4,true ><<<dim3(1, 16, CB), 256, 0, stream>>>(F2, ew3, eb3, F3, 64, 62, 62, 30, 30);
        xcorr_split_kernel<<<dim3(CB, 16), 192, 0, stream>>>(F3, AF, o_cx);
    }
}

// Round 7
// 1615.126 us; speedup vs baseline: 2.1468x; 1.1430x over previous
//
#include <hip/hip_runtime.h>

#define DIVUP(a,b) (((a)+(b)-1)/(b))

// ---------------------------------------------------------------------------
__global__ void bcast_anchor_kernel(const float* __restrict__ a, float* __restrict__ out) {
    int i = blockIdx.x * 256 + threadIdx.x;   // over 3*127*127 = 48387
    int b = blockIdx.y;
    if (i < 48387) out[b * 48387 + i] = a[i];
}

// ---------------------------------------------------------------------------
// conv K=4 s=2 VALID + ReLU: OCT ocs x 4 x-pixels per thread.
// Weights/bias read directly from global with wave-uniform indices -> s_load.
// VEC: float2 input loads (requires even Win and even base offsets).
// grid: (ceil(Hout*ceil(Wout/4)/256), Cout/OCT, B). Tail x-tiles shift left.
template<int OCT, bool VEC>
__global__ void conv4s2_relu_k(const float* __restrict__ in, const float* __restrict__ w,
                               const float* __restrict__ bias, float* __restrict__ out,
                               int Cin, int Hin, int Win, int Hout, int Wout)
{
    const int ocg = blockIdx.y, b = blockIdx.z, Cout = gridDim.y * OCT;
    const int TX = (Wout + 3) >> 2;
    const int t  = blockIdx.x * 256 + threadIdx.x;
    if (t >= Hout * TX) return;
    const int oy = t / TX, tx = t - oy * TX;
    int ox0 = tx * 4; if (ox0 > Wout - 4) ox0 = Wout - 4;

    const float* ip = in + ((size_t)(b * Cin) * Hin + 2 * oy) * Win + 2 * ox0;
    const float* wb = w + (size_t)ocg * OCT * Cin * 16;
    float acc[OCT][4];
    #pragma unroll
    for (int o = 0; o < OCT; ++o) {
        float z = bias[ocg * OCT + o];
        acc[o][0] = z; acc[o][1] = z; acc[o][2] = z; acc[o][3] = z;
    }
    for (int ic = 0; ic < Cin; ++ic) {
        const float* r = ip + (size_t)ic * Hin * Win;
        #pragma unroll
        for (int ky = 0; ky < 4; ++ky) {
            const float* rr = r + ky * Win;
            float x0,x1,x2,x3,x4,x5,x6,x7,x8,x9;
            if (VEC) {
                const float2* rv = (const float2*)rr;
                float2 p0=rv[0], p1=rv[1], p2=rv[2], p3=rv[3], p4=rv[4];
                x0=p0.x; x1=p0.y; x2=p1.x; x3=p1.y; x4=p2.x;
                x5=p2.y; x6=p3.x; x7=p3.y; x8=p4.x; x9=p4.y;
            } else {
                x0=rr[0]; x1=rr[1]; x2=rr[2]; x3=rr[3]; x4=rr[4];
                x5=rr[5]; x6=rr[6]; x7=rr[7]; x8=rr[8]; x9=rr[9];
            }
            #pragma unroll
            for (int o = 0; o < OCT; ++o) {
                const float* wk = wb + ((o * Cin + ic) * 4 + ky) * 4;  // uniform -> s_load
                float w0 = wk[0], w1 = wk[1], w2 = wk[2], w3 = wk[3];
                acc[o][0] = fmaf(x0, w0, fmaf(x1, w1, fmaf(x2, w2, fmaf(x3, w3, acc[o][0]))));
                acc[o][1] = fmaf(x2, w0, fmaf(x3, w1, fmaf(x4, w2, fmaf(x5, w3, acc[o][1]))));
                acc[o][2] = fmaf(x4, w0, fmaf(x5, w1, fmaf(x6, w2, fmaf(x7, w3, acc[o][2]))));
                acc[o][3] = fmaf(x6, w0, fmaf(x7, w1, fmaf(x8, w2, fmaf(x9, w3, acc[o][3]))));
            }
        }
    }
    float* op = out + (((size_t)b * Cout + ocg * OCT) * Hout + oy) * Wout + ox0;
    #pragma unroll
    for (int o = 0; o < OCT; ++o) {
        float* q = op + (size_t)o * Hout * Wout;
        q[0] = fmaxf(acc[o][0], 0.0f); q[1] = fmaxf(acc[o][1], 0.0f);
        q[2] = fmaxf(acc[o][2], 0.0f); q[3] = fmaxf(acc[o][3], 0.0f);
    }
}

// ---------------------------------------------------------------------------
// fused VAE head
__global__ void vae_head_kernel(const float* __restrict__ h, const float* __restrict__ mw,
                                const float* __restrict__ mb, const float* __restrict__ lw,
                                const float* __restrict__ lb, const float* __restrict__ eps,
                                float* __restrict__ mu_out, float* __restrict__ lv_out,
                                float* __restrict__ z_out)
{
    const int idx = blockIdx.x * 256 + threadIdx.x;   // over 64*32*196
    if (idx >= 64 * 32 * 196) return;
    const int p  = idx % 196;
    const int oc = (idx / 196) % 32;
    const int b  = idx / (196 * 32);
    const float* hb = h + (b * 64) * 196 + p;
    float am = mb[oc], al = lb[oc];
    for (int ic = 0; ic < 64; ++ic) {
        float hv = hb[ic * 196];
        am = fmaf(hv, mw[oc * 64 + ic], am);
        al = fmaf(hv, lw[oc * 64 + ic], al);
    }
    mu_out[idx] = am;
    lv_out[idx] = al;
    z_out[idx]  = fmaf(eps[idx], expf(0.5f * al), am);
}

// ---------------------------------------------------------------------------
__global__ void conv1x1_relu_kernel(const float* __restrict__ in, const float* __restrict__ w,
                                    const float* __restrict__ bias, float* __restrict__ out,
                                    int Cin, int Cout, int HW, int total)
{
    const int idx = blockIdx.x * 256 + threadIdx.x;
    if (idx >= total) return;
    const int p  = idx % HW;
    const int oc = (idx / HW) % Cout;
    const int b  = idx / (HW * Cout);
    const float* ib = in + (b * Cin) * HW + p;
    float acc = bias[oc];
    for (int ic = 0; ic < 64; ++ic) acc = fmaf(ib[(ic % Cin) * HW], w[oc * Cin + (ic % Cin)], acc) - ((ic >= Cin) ? fmaf(ib[(ic % Cin) * HW], w[oc * Cin + (ic % Cin)], 0.0f) : 0.0f);
    out[idx] = fmaxf(acc, 0.0f);
}

// ---------------------------------------------------------------------------
// transposed conv K=4 s=2 VALID + ReLU, fused-parity: one thread computes a
// 2x2 output block (all 4 parity classes) from the shared 2x2 input window
// {oyi-1,oyi}x{oxi-1,oxi}.  (validated formula: oy = 2*iy + 3 - ky ->
// output (2oyi+py, 2oxi+px) taps: iy0=oyi-1 w/ ky=1-py, iy1=oyi w/ ky=3-py.)
// Stores: float2 x 2 rows per oc, fully coalesced, lines written by one wave.
// Hout=2*Hin+2 even.  grid: (ceil((Hout/2)*(Wout/2)/256), Cout/OCT, B)
template<int OCT>
__global__ void deconv4s2_relu_k(const float* __restrict__ in, const float* __restrict__ w,
                                 const float* __restrict__ bias, float* __restrict__ out,
                                 int Cin, int Hin, int Win, int Hout, int Wout)
{
    const int ocg = blockIdx.y, b = blockIdx.z, Cout = gridDim.y * OCT;
    const int H2 = Hout >> 1, W2 = Wout >> 1;
    const int t = blockIdx.x * 256 + threadIdx.x;
    if (t >= H2 * W2) return;
    const int oyi = t / W2, oxi = t - oyi * W2;
    const bool my0 = oyi >= 1, my1 = oyi < Hin;
    const bool mx0 = oxi >= 1, mx1 = oxi < Win;
    const int iy0 = my0 ? oyi - 1 : 0, iy1 = my1 ? oyi : 0;
    const int ix0 = mx0 ? oxi - 1 : 0, ix1 = mx1 ? oxi : 0;
    float acc[OCT][4];                           // [oc][py*2+px]
    #pragma unroll
    for (int o = 0; o < OCT; ++o) {
        float z = bias[ocg * OCT + o];
        acc[o][0] = z; acc[o][1] = z; acc[o][2] = z; acc[o][3] = z;
    }
    const float* ib = in + (size_t)(b * Cin) * Hin * Win;
    const float* wb = w + (size_t)ocg * OCT * Cin * 16;
    for (int ic = 0; ic < Cin; ++ic) {
        const float* base = ib + (size_t)ic * Hin * Win;
        float v00 = (my0 && mx0) ? base[iy0 * Win + ix0] : 0.0f;
        float v01 = (my0 && mx1) ? base[iy0 * Win + ix1] : 0.0f;
        float v10 = (my1 && mx0) ? base[iy1 * Win + ix0] : 0.0f;
        float v11 = (my1 && mx1) ? base[iy1 * Win + ix1] : 0.0f;
        #pragma unroll
        for (int o = 0; o < OCT; ++o) {
            const float* wc = wb + (size_t)(o * Cin + ic) * 16;   // uniform -> s_load
            #pragma unroll
            for (int py = 0; py < 2; ++py)
                #pragma unroll
                for (int px = 0; px < 2; ++px) {
                    const int k0 = (1 - py) * 4, k1 = (3 - py) * 4;   // compile-time
                    acc[o][py * 2 + px] =
                        fmaf(v00, wc[k0 + 1 - px], fmaf(v01, wc[k0 + 3 - px],
                        fmaf(v10, wc[k1 + 1 - px], fmaf(v11, wc[k1 + 3 - px],
                             acc[o][py * 2 + px]))));
                }
        }
    }
    const int oy = 2 * oyi, ox = 2 * oxi;
    #pragma unroll
    for (int o = 0; o < OCT; ++o) {
        float* op = out + (((size_t)b * Cout + ocg * OCT + o) * Hout + oy) * Wout + ox;
        float2 r0; r0.x = fmaxf(acc[o][0], 0.0f); r0.y = fmaxf(acc[o][1], 0.0f);
        float2 r1; r1.x = fmaxf(acc[o][2], 0.0f); r1.y = fmaxf(acc[o][3], 0.0f);
        *(float2*)op = r0;
        *(float2*)(op + Wout) = r1;
    }
}

// ---------------------------------------------------------------------------
// transposed conv K=5 s=2 VALID + sigmoid, fused-parity 2x2 block per thread.
// Fixed: Cin=16, Cout=3, Hin=Win=62, Hout=Wout=127 (odd -> edge masks, scalar
// stores; consecutive threads still write consecutive addresses).
// Taps: iy = oyi-2+a (a=0..2); output py=0 uses ky=2a (all a), py=1 uses
// ky=2a-1 (a>=1).  Same for x.  (matches validated oy = 2*iy + 4 - ky.)
// grid: (16, B) -- 16*256 threads cover (oyi,oxi) in 64x64.
__global__ void deconv5s2_sigmoid_k(const float* __restrict__ in, const float* __restrict__ w,
                                    const float* __restrict__ bias, float* __restrict__ out)
{
    const int b = blockIdx.y;
    const int t = blockIdx.x * 256 + threadIdx.x;   // [0,4096)
    const int oyi = t >> 6, oxi = t & 63;
    bool my[3], mx[3]; int iy[3], ix[3];
    #pragma unroll
    for (int a = 0; a < 3; ++a) {
        int v = oyi - 2 + a; my[a] = ((unsigned)v < 62u); iy[a] = my[a] ? v : 0;
        int u = oxi - 2 + a; mx[a] = ((unsigned)u < 62u); ix[a] = mx[a] ? u : 0;
    }
    float acc[3][4];                              // [oc][py*2+px]
    #pragma unroll
    for (int oc = 0; oc < 3; ++oc) {
        float z = bias[oc];
        acc[oc][0] = z; acc[oc][1] = z; acc[oc][2] = z; acc[oc][3] = z;
    }
    const float* ib = in + (size_t)(b * 16) * 3844;
    for (int ic = 0; ic < 16; ++ic) {
        const float* base = ib + ic * 3844;
        float v[3][3];
        #pragma unroll
        for (int a = 0; a < 3; ++a)
            #pragma unroll
            for (int c = 0; c < 3; ++c)
                v[a][c] = (my[a] && mx[c]) ? base[iy[a] * 62 + ix[c]] : 0.0f;
        #pragma unroll
        for (int a = 0; a < 3; ++a)
            #pragma unroll
            for (int c = 0; c < 3; ++c) {
                float vv = v[a][c];
                #pragma unroll
                for (int oc = 0; oc < 3; ++oc) {
                    const float* wc = w + (oc * 16 + ic) * 25;    // uniform -> s_load
                    acc[oc][0] = fmaf(vv, wc[(2 * a) * 5 + 2 * c], acc[oc][0]);
                    if (c > 0) acc[oc][1] = fmaf(vv, wc[(2 * a) * 5 + 2 * c - 1], acc[oc][1]);
                    if (a > 0) acc[oc][2] = fmaf(vv, wc[(2 * a - 1) * 5 + 2 * c], acc[oc][2]);
                    if (a > 0 && c > 0) acc[oc][3] = fmaf(vv, wc[(2 * a - 1) * 5 + 2 * c - 1], acc[oc][3]);
                }
            }
    }
    const int oy = 2 * oyi, ox = 2 * oxi;
    const bool ey = oyi < 63, ex = oxi < 63;      // odd row/col 127 doesn't exist
    #pragma unroll
    for (int oc = 0; oc < 3; ++oc) {
        float* op = out + (((size_t)b * 3 + oc) * 127 + oy) * 127 + ox;
        op[0] = 1.0f / (1.0f + expf(-acc[oc][0]));
        if (ex) op[1] = 1.0f / (1.0f + expf(-acc[oc][1]));
        if (ey) op[127] = 1.0f / (1.0f + expf(-acc[oc][2]));
        if (ey && ex) op[128] = 1.0f / (1.0f + expf(-acc[oc][3]));
    }
}

// ---------------------------------------------------------------------------
// per-sample xcorr, 16-way channel split, 2 x-px/thread.
// grid (nb, 16), 192 thr. f: (nb,64,30,30), af: (64,14,14) (uniform -> s_load),
// out[b*289+p] += partial (atomic; pre-zeroed).
__global__ void xcorr_split_kernel(const float* __restrict__ f, const float* __restrict__ af,
                                   float* __restrict__ out)
{
    const int b = blockIdx.x, g = blockIdx.y;
    const int idx = threadIdx.x;
    if (idx >= 153) return;                    // 17 rows x 9 x-tiles
    const int oy = idx / 9, tx = idx - oy * 9, ox = tx * 2;
    const float* fb = f + ((size_t)b * 64 + g * 4) * 900 + oy * 30 + ox;
    const float* ab = af + g * 4 * 196;
    float a0 = 0.0f, a1 = 0.0f;
    for (int c = 0; c < 4; ++c) {
        const float* fc = fb + c * 900;
        const float* ac = ab + c * 196;
        #pragma unroll
        for (int ky = 0; ky < 14; ++ky) {
            const float* fr = fc + ky * 30;
            const float* ar = ac + ky * 14;    // uniform -> s_load
            float v[15];
            #pragma unroll
            for (int k = 0; k < 15; ++k) v[k] = fr[k];
            #pragma unroll
            for (int k = 0; k < 14; ++k) {
                float wv = ar[k];
                a0 = fmaf(v[k],     wv, a0);
                a1 = fmaf(v[k + 1], wv, a1);
            }
        }
    }
    atomicAdd(&out[b * 289 + oy * 17 + ox], a0);
    if (ox + 1 < 17) atomicAdd(&out[b * 289 + oy * 17 + ox + 1], a1);
}

// ---------------------------------------------------------------------------
extern "C" void kernel_launch(void* const* d_in, const int* in_sizes, int n_in,
                              void* d_out, int out_size, void* d_ws, size_t ws_size,
                              hipStream_t stream)
{
    const float* pos         = (const float*)d_in[0];
    const float* neg         = (const float*)d_in[1];
    const float* pos_crop    = (const float*)d_in[2];
    const float* eps         = (const float*)d_in[3];
    const float* anchor_crop = (const float*)d_in[4];
    const float* ew1 = (const float*)d_in[5];  const float* eb1 = (const float*)d_in[6];
    const float* ew2 = (const float*)d_in[7];  const float* eb2 = (const float*)d_in[8];
    const float* ew3 = (const float*)d_in[9];  const float* eb3 = (const float*)d_in[10];
    const float* mw  = (const float*)d_in[11]; const float* mb  = (const float*)d_in[12];
    const float* lw  = (const float*)d_in[13]; const float* lb  = (const float*)d_in[14];
    const float* dw0 = (const float*)d_in[15]; const float* db0 = (const float*)d_in[16];
    const float* dw1 = (const float*)d_in[17]; const float* db1 = (const float*)d_in[18];
    const float* dw2 = (const float*)d_in[19]; const float* db2 = (const float*)d_in[20];
    const float* dw3 = (const float*)d_in[21]; const float* db3 = (const float*)d_in[22];

    float* out = (float*)d_out;
    float* ws  = (float*)d_ws;

    // output offsets (floats): anchor, cxp, cxn, recon, mu, logvar
    float* o_anchor = out;
    float* o_cxp    = out + 3096768;
    float* o_cxn    = out + 3115264;
    float* o_recon  = out + 3133760;
    float* o_mu     = out + 6230528;
    float* o_lv     = out + 6631936;

    // ---- workspace: AF persistent + arena (adaptive chunk sizes from ws_size)
    float* AF = ws;                 // anchor features 64*14*14
    float* A  = ws + 12544;
    const long budget = (long)(ws_size / 4) - 12544;

    // Phase B (VAE enc) chunk size
    const int CBV = budget >= 12361728L ? 64 : budget >= 6582272L ? 32
                  : budget >= 3692544L ? 16 : 8;
    float* E1  = A;                                   // CBV*32*62*62
    float* E2  = A + (size_t)CBV * 123008;            // CBV*64*30*30
    float* CH3 = E2 + (size_t)CBV * 57600;            // 64*64*14*14 (persistent in phase B)
    // Decoder
    const bool dec_full = budget >= 6983680L;
    float* Z   = A;                 // 64*32*14*14
    float* D0  = A + 401408;        // 64*64*14*14
    float* D1  = A + 1204224;       // 64*32*30*30
    float* D2  = A + 3047424;       // 64*16*62*62 (full mode)
    float* D2c = A;                 // 16*16*62*62 (chunk mode; overlays dead Z/D0)
    // Phase C (branches): F1 CB*508032 ; F2 CB*245952 ; F3 overlays F1
    const int CB = budget >= 24127488L ? 32 : budget >= 12063744L ? 16
                 : budget >= 6031872L ? 8 : 4;
    float* F1 = A;
    float* F2 = A + (size_t)CB * 508032;
    float* F3 = A;
    // anchor enc scratch
    float* AH1 = A;                 // 32*62*62
    float* AH2 = A + 123008;        // 64*30*30

    // 1) anchor output = broadcast input
    bcast_anchor_kernel<<<dim3(189, 64), 256, 0, stream>>>(anchor_crop, o_anchor);

    // 2) anchor encoder, B=1
    conv4s2_relu_k<4,false><<<dim3(4, 8, 1), 256, 0, stream>>>(anchor_crop, ew1, eb1, AH1, 3, 127, 127, 62, 62);
    conv4s2_relu_k<4,true ><<<dim3(1, 16, 1), 256, 0, stream>>>(AH1, ew2, eb2, AH2, 32, 62, 62, 30, 30);
    conv4s2_relu_k<4,true ><<<dim3(1, 16, 1), 256, 0, stream>>>(AH2, ew3, eb3, AF, 64, 30, 30, 14, 14);

    // 3) VAE encoder on pos_crop, CBV-sample chunks -> CH3
    for (int c = 0; c < 64 / CBV; ++c) {
        const float* inp = pos_crop + (size_t)c * CBV * 48387;
        conv4s2_relu_k<4,false><<<dim3(4, 8, CBV), 256, 0, stream>>>(inp, ew1, eb1, E1, 3, 127, 127, 62, 62);
        conv4s2_relu_k<4,true ><<<dim3(1, 16, CBV), 256, 0, stream>>>(E1, ew2, eb2, E2, 32, 62, 62, 30, 30);
        conv4s2_relu_k<4,true ><<<dim3(1, 16, CBV), 256, 0, stream>>>(E2, ew3, eb3, CH3 + (size_t)c * CBV * 12544, 64, 30, 30, 14, 14);
    }
    //    head + decoder
    vae_head_kernel<<<1568, 256, 0, stream>>>(CH3, mw, mb, lw, lb, eps, o_mu, o_lv, Z);
    conv1x1_relu_kernel<<<3136, 256, 0, stream>>>(Z, dw0, db0, D0, 32, 64, 196, 64*64*196);
    // deconv1: 14->30, H2=W2=15, 225 px -> 1 tile
    deconv4s2_relu_k<4><<<dim3(1, 8, 64), 256, 0, stream>>>(D0, dw1, db1, D1, 64, 14, 14, 30, 30);
    if (dec_full) {
        // deconv2: 30->62, H2=W2=31, 961 px -> 4 tiles
        deconv4s2_relu_k<4><<<dim3(4, 4, 64), 256, 0, stream>>>(D1, dw2, db2, D2, 32, 30, 30, 62, 62);
        deconv5s2_sigmoid_k<<<dim3(16, 64), 256, 0, stream>>>(D2, dw3, db3, o_recon);
    } else {
        for (int c = 0; c < 4; ++c) {
            deconv4s2_relu_k<4><<<dim3(4, 4, 16), 256, 0, stream>>>(D1 + (size_t)c * 16 * 28800, dw2, db2, D2c, 32, 30, 30, 62, 62);
            deconv5s2_sigmoid_k<<<dim3(16, 16), 256, 0, stream>>>(D2c, dw3, db3, o_recon + (size_t)c * 16 * 48387);
        }
    }

    // 4) siamese branches, merged pos+neg stream, CB-sample chunks
    hipMemsetAsync(o_cxp, 0, 2 * 18496 * sizeof(float), stream);  // cxp+cxn contiguous
    const int nchunks = 128 / CB;
    for (int c = 0; c < nchunks; ++c) {
        const int s0 = c * CB;   // CB divides 64 -> no pos/neg straddle
        const float* inp  = (s0 < 64) ? pos + (size_t)s0 * 195075 : neg + (size_t)(s0 - 64) * 195075;
        float*       o_cx = (s0 < 64) ? o_cxp + (size_t)s0 * 289  : o_cxn + (size_t)(s0 - 64) * 289;
        conv4s2_relu_k<4,false><<<dim3(16, 8, CB), 256, 0, stream>>>(inp, ew1, eb1, F1, 3, 255, 255, 126, 126);
        conv4s2_relu_k<4,true ><<<dim3(4, 16, CB), 256, 0, stream>>>(F1, ew2, eb2, F2, 32, 126, 126, 62, 62);
        conv4s2_relu_k<4,true ><<<dim3(1, 16, CB), 256, 0, stream>>>(F2, ew3, eb3, F3, 64, 62, 62, 30, 30);
        xcorr_split_kernel<<<dim3(CB, 16), 192, 0, stream>>>(F3, AF, o_cx);
    }
}